// Round 3
// baseline (1430.908 us; speedup 1.0000x reference)
//
#include <hip/hip_runtime.h>
#include <cstdint>
#include <cstddef>

#define EPS 1e-6f
#define KAPPA 20.0f

#define B 16
#define C 512
#define N 4096
#define J 6        // 0..2 fg, 3..5 bg
#define NT 128     // n-tile per block
#define NTILES (N / NT)  // 32

// ---------------- init: normalize mu0 over c, broadcast to all b & both models; zero acc ----------------
__global__ __launch_bounds__(512) void pmms_init(const float* __restrict__ mu_in,
                                                 float* __restrict__ mu_cur,
                                                 float* __restrict__ mu_acc) {
  int b = blockIdx.x;
  int c = threadIdx.x; // 0..511
  float v0 = mu_in[c * 3 + 0], v1 = mu_in[c * 3 + 1], v2 = mu_in[c * 3 + 2];
  float s0 = v0 * v0, s1 = v1 * v1, s2 = v2 * v2;
  for (int o = 32; o; o >>= 1) {
    s0 += __shfl_down(s0, o);
    s1 += __shfl_down(s1, o);
    s2 += __shfl_down(s2, o);
  }
  __shared__ float r[8][3];
  int w = c >> 6, ln = c & 63;
  if (ln == 0) { r[w][0] = s0; r[w][1] = s1; r[w][2] = s2; }
  __syncthreads();
  float t0 = 0.f, t1 = 0.f, t2 = 0.f;
  for (int i = 0; i < 8; ++i) { t0 += r[i][0]; t1 += r[i][1]; t2 += r[i][2]; }
  float sc0 = 1.0f / (EPS + sqrtf(t0));
  float sc1 = 1.0f / (EPS + sqrtf(t1));
  float sc2 = 1.0f / (EPS + sqrtf(t2));
  float n0 = v0 * sc0, n1 = v1 * sc1, n2 = v2 * sc2;
  size_t base = ((size_t)b * C + c) * J;
  mu_cur[base + 0] = n0; mu_cur[base + 1] = n1; mu_cur[base + 2] = n2;
  mu_cur[base + 3] = n0; mu_cur[base + 4] = n1; mu_cur[base + 5] = n2;
  #pragma unroll
  for (int j = 0; j < J; ++j) mu_acc[base + j] = 0.0f;
}

// ---------------- one EM stage, fg+bg fused; x read straight from L3 (no x staging) ----------------
// grid 512 = 16 b * 32 tiles of 128 n; 256 threads
__global__ __launch_bounds__(256, 6) void pmms_stage(const float* __restrict__ feat,
                                                     const float* __restrict__ mask,
                                                     const float* __restrict__ mu_cur,
                                                     float* __restrict__ mu_acc) {
  __shared__ float mus[C * 8];   // [c][8], j 0..5 used
  __shared__ float zs[J][NT];    // z transposed: row j, broadcast-read in M-step
  __shared__ float ms[NT];       // mask tile

  const int b  = blockIdx.x >> 5;
  const int n0 = (blockIdx.x & 31) * NT;
  const int tid = threadIdx.x;

  for (int i = tid; i < C * J; i += 256) {
    int c = i / 6, j = i - c * 6;
    mus[c * 8 + j] = mu_cur[(size_t)b * C * J + i];
  }
  if (tid < NT / 4) {
    *(float4*)(ms + tid * 4) = *(const float4*)(mask + (size_t)b * N + n0 + tid * 4);
  }
  __syncthreads();

  // ---- E-step: thread = (4 n) x (64 interleaved c); shuffle-reduce over 8 c-chunks ----
  {
    const int cc = tid & 7, ng = tid >> 3;      // ng 0..31
    const int nb = n0 + ng * 4;
    float4 m4 = *(const float4*)(ms + ng * 4);  // broadcast over cc
    float L[J][4];
    #pragma unroll
    for (int j = 0; j < J; ++j)
      #pragma unroll
      for (int k = 0; k < 4; ++k) L[j][k] = 0.0f;
    const float* fb = feat + (size_t)b * C * N + nb;
    #pragma unroll 4
    for (int i = 0; i < C / 8; ++i) {
      int c = cc + i * 8;                       // interleaved: mus reads <=2-way bank conflict
      float4 f   = *(const float4*)(fb + (size_t)c * N);
      float4 m03 = *(const float4*)(mus + c * 8);
      float2 m45 = *(const float2*)(mus + c * 8 + 4);
      float fa[4] = {f.x, f.y, f.z, f.w};
      float ma[4] = {m4.x, m4.y, m4.z, m4.w};
      #pragma unroll
      for (int k = 0; k < 4; ++k) {
        float xf = ma[k] * fa[k];
        float xb = fa[k] - xf;
        L[0][k] = fmaf(xf, m03.x, L[0][k]);
        L[1][k] = fmaf(xf, m03.y, L[1][k]);
        L[2][k] = fmaf(xf, m03.z, L[2][k]);
        L[3][k] = fmaf(xb, m03.w, L[3][k]);
        L[4][k] = fmaf(xb, m45.x, L[4][k]);
        L[5][k] = fmaf(xb, m45.y, L[5][k]);
      }
    }
    #pragma unroll
    for (int d = 1; d < 8; d <<= 1)
      #pragma unroll
      for (int j = 0; j < J; ++j)
        #pragma unroll
        for (int k = 0; k < 4; ++k)
          L[j][k] += __shfl_xor(L[j][k], d);
    // softmax (kappa) per model; all lanes compute (uniform), cc==0 writes
    float zv[J][4];
    #pragma unroll
    for (int k = 0; k < 4; ++k) {
      float mf = fmaxf(fmaxf(L[0][k], L[1][k]), L[2][k]);
      float e0 = __expf(KAPPA * (L[0][k] - mf));
      float e1 = __expf(KAPPA * (L[1][k] - mf));
      float e2 = __expf(KAPPA * (L[2][k] - mf));
      float is = 1.0f / (e0 + e1 + e2);
      zv[0][k] = e0 * is; zv[1][k] = e1 * is; zv[2][k] = e2 * is;
      float mb = fmaxf(fmaxf(L[3][k], L[4][k]), L[5][k]);
      e0 = __expf(KAPPA * (L[3][k] - mb));
      e1 = __expf(KAPPA * (L[4][k] - mb));
      e2 = __expf(KAPPA * (L[5][k] - mb));
      is = 1.0f / (e0 + e1 + e2);
      zv[3][k] = e0 * is; zv[4][k] = e1 * is; zv[5][k] = e2 * is;
    }
    if (cc == 0) {
      int nl = ng * 4;
      #pragma unroll
      for (int j = 0; j < J; ++j)
        *(float4*)(&zs[j][nl]) = make_float4(zv[j][0], zv[j][1], zv[j][2], zv[j][3]);
    }
  }
  __syncthreads();

  // ---- M-step: thread = 2 c rows; z/mask broadcast from LDS ----
  float acc[12];
  #pragma unroll
  for (int j = 0; j < 12; ++j) acc[j] = 0.0f;
  {
    const int c0 = tid, c1 = tid + 256;
    const float* f0p = feat + ((size_t)b * C + c0) * N + n0;
    const float* f1p = feat + ((size_t)b * C + c1) * N + n0;
    #pragma unroll 2
    for (int g = 0; g < NT / 4; ++g) {
      float4 f0 = *(const float4*)(f0p + g * 4);
      float4 f1 = *(const float4*)(f1p + g * 4);
      float4 mm = *(const float4*)(ms + g * 4);
      float4 z0 = *(const float4*)(&zs[0][g * 4]);
      float4 z1 = *(const float4*)(&zs[1][g * 4]);
      float4 z2 = *(const float4*)(&zs[2][g * 4]);
      float4 z3 = *(const float4*)(&zs[3][g * 4]);
      float4 z4 = *(const float4*)(&zs[4][g * 4]);
      float4 z5 = *(const float4*)(&zs[5][g * 4]);
      float fa0[4] = {f0.x, f0.y, f0.z, f0.w};
      float fa1[4] = {f1.x, f1.y, f1.z, f1.w};
      float mk[4]  = {mm.x, mm.y, mm.z, mm.w};
      float za[J][4] = {{z0.x,z0.y,z0.z,z0.w},{z1.x,z1.y,z1.z,z1.w},{z2.x,z2.y,z2.z,z2.w},
                        {z3.x,z3.y,z3.z,z3.w},{z4.x,z4.y,z4.z,z4.w},{z5.x,z5.y,z5.z,z5.w}};
      #pragma unroll
      for (int k = 0; k < 4; ++k) {
        float xf = mk[k] * fa0[k], xb = fa0[k] - xf;
        acc[0] = fmaf(xf, za[0][k], acc[0]);
        acc[1] = fmaf(xf, za[1][k], acc[1]);
        acc[2] = fmaf(xf, za[2][k], acc[2]);
        acc[3] = fmaf(xb, za[3][k], acc[3]);
        acc[4] = fmaf(xb, za[4][k], acc[4]);
        acc[5] = fmaf(xb, za[5][k], acc[5]);
        xf = mk[k] * fa1[k]; xb = fa1[k] - xf;
        acc[6]  = fmaf(xf, za[0][k], acc[6]);
        acc[7]  = fmaf(xf, za[1][k], acc[7]);
        acc[8]  = fmaf(xf, za[2][k], acc[8]);
        acc[9]  = fmaf(xb, za[3][k], acc[9]);
        acc[10] = fmaf(xb, za[4][k], acc[10]);
        acc[11] = fmaf(xb, za[5][k], acc[11]);
      }
    }
  }
  float* dst = mu_acc + (size_t)b * C * J;
  #pragma unroll
  for (int j = 0; j < 6; ++j) atomicAdd(dst + tid * 6 + j, acc[j]);
  #pragma unroll
  for (int j = 0; j < 6; ++j) atomicAdd(dst + (size_t)(tid + 256) * 6 + j, acc[6 + j]);
}

// ---------------- L2-normalize mu over c; re-zero acc; optionally emit mu_f/mu_b ----------------
__global__ __launch_bounds__(256) void pmms_norm(float* __restrict__ mu_acc,
                                                 float* __restrict__ mu_cur,
                                                 float* __restrict__ out_f,
                                                 float* __restrict__ out_b,
                                                 int write_out) {
  int b = blockIdx.x / 6, j = blockIdx.x % 6;
  int tid = threadIdx.x;
  size_t base = (size_t)b * C * J + j;
  float v0 = mu_acc[base + (size_t)tid * 6];
  float v1 = mu_acc[base + (size_t)(tid + 256) * 6];
  float ss = v0 * v0 + v1 * v1;
  for (int o = 32; o; o >>= 1) ss += __shfl_down(ss, o);
  __shared__ float r[4];
  if ((tid & 63) == 0) r[tid >> 6] = ss;
  __syncthreads();
  float tot = r[0] + r[1] + r[2] + r[3];
  float sc = 1.0f / (EPS + sqrtf(tot));
  float n0 = v0 * sc, n1 = v1 * sc;
  mu_cur[base + (size_t)tid * 6] = n0;
  mu_cur[base + (size_t)(tid + 256) * 6] = n1;
  mu_acc[base + (size_t)tid * 6] = 0.0f;
  mu_acc[base + (size_t)(tid + 256) * 6] = 0.0f;
  if (write_out) {
    float* o = (j < 3) ? (out_f + (size_t)b * 1536 + j * 512)
                       : (out_b + (size_t)b * 1536 + (j - 3) * 512);
    o[tid] = n0;
    o[tid + 256] = n1;
  }
}

// ---------------- final discriminative pass on query (no kappa) ----------------
// grid 512 = 16 b * 32 tiles of 128 n; 256 threads
__global__ __launch_bounds__(256, 6) void pmms_query(const float* __restrict__ q,
                                                     const float* __restrict__ mu_cur,
                                                     float* __restrict__ P,
                                                     float* __restrict__ PM) {
  __shared__ float mus[C * 8];
  const int b  = blockIdx.x >> 5;
  const int n0 = (blockIdx.x & 31) * NT;
  const int tid = threadIdx.x;
  for (int i = tid; i < C * J; i += 256) {
    int c = i / 6, j = i - c * 6;
    mus[c * 8 + j] = mu_cur[(size_t)b * C * J + i];
  }
  __syncthreads();
  const int cc = tid & 7, ng = tid >> 3;
  const int nb = n0 + ng * 4;
  float L[J][4];
  #pragma unroll
  for (int j = 0; j < J; ++j)
    #pragma unroll
    for (int k = 0; k < 4; ++k) L[j][k] = 0.0f;
  const float* qb = q + (size_t)b * C * N + nb;
  #pragma unroll 4
  for (int i = 0; i < C / 8; ++i) {
    int c = cc + i * 8;
    float4 f   = *(const float4*)(qb + (size_t)c * N);
    float4 m03 = *(const float4*)(mus + c * 8);
    float2 m45 = *(const float2*)(mus + c * 8 + 4);
    float fa[4] = {f.x, f.y, f.z, f.w};
    #pragma unroll
    for (int k = 0; k < 4; ++k) {
      L[0][k] = fmaf(fa[k], m03.x, L[0][k]);
      L[1][k] = fmaf(fa[k], m03.y, L[1][k]);
      L[2][k] = fmaf(fa[k], m03.z, L[2][k]);
      L[3][k] = fmaf(fa[k], m03.w, L[3][k]);
      L[4][k] = fmaf(fa[k], m45.x, L[4][k]);
      L[5][k] = fmaf(fa[k], m45.y, L[5][k]);
    }
  }
  #pragma unroll
  for (int d = 1; d < 8; d <<= 1)
    #pragma unroll
    for (int j = 0; j < J; ++j)
      #pragma unroll
      for (int k = 0; k < 4; ++k)
        L[j][k] += __shfl_xor(L[j][k], d);
  // softmax over all 6 (no kappa)
  float zv[J][4];
  #pragma unroll
  for (int k = 0; k < 4; ++k) {
    float mx = fmaxf(fmaxf(fmaxf(L[0][k], L[1][k]), fmaxf(L[2][k], L[3][k])), fmaxf(L[4][k], L[5][k]));
    float e0 = __expf(L[0][k] - mx), e1 = __expf(L[1][k] - mx), e2 = __expf(L[2][k] - mx);
    float e3 = __expf(L[3][k] - mx), e4 = __expf(L[4][k] - mx), e5 = __expf(L[5][k] - mx);
    float is = 1.0f / (e0 + e1 + e2 + e3 + e4 + e5);
    zv[0][k] = e0 * is; zv[1][k] = e1 * is; zv[2][k] = e2 * is;
    zv[3][k] = e3 * is; zv[4][k] = e4 * is; zv[5][k] = e5 * is;
  }
  if (cc == 0) {
    float* Pb = P + (size_t)b * 6 * N;
    #pragma unroll
    for (int j = 0; j < J; ++j)
      *(float4*)(Pb + (size_t)j * N + nb) = make_float4(zv[j][0], zv[j][1], zv[j][2], zv[j][3]);
    float* pm = PM + (size_t)b * 2 * N;
    *(float4*)(pm + nb) = make_float4(zv[3][0] + zv[4][0] + zv[5][0],
                                      zv[3][1] + zv[4][1] + zv[5][1],
                                      zv[3][2] + zv[4][2] + zv[5][2],
                                      zv[3][3] + zv[4][3] + zv[5][3]);
    *(float4*)(pm + N + nb) = make_float4(zv[0][0] + zv[1][0] + zv[2][0],
                                          zv[0][1] + zv[1][1] + zv[2][1],
                                          zv[0][2] + zv[1][2] + zv[2][2],
                                          zv[0][3] + zv[1][3] + zv[2][3]);
  }
}

extern "C" void kernel_launch(void* const* d_in, const int* in_sizes, int n_in,
                              void* d_out, int out_size, void* d_ws, size_t ws_size,
                              hipStream_t stream) {
  const float* feat  = (const float*)d_in[0];
  const float* mask  = (const float*)d_in[1];
  const float* query = (const float*)d_in[2];
  const float* mu_in = (const float*)d_in[3];
  float* out = (float*)d_out;

  float* mu_cur = (float*)d_ws;            // [B][C][J]
  float* mu_acc = mu_cur + (size_t)B * C * J;

  pmms_init<<<B, 512, 0, stream>>>(mu_in, mu_cur, mu_acc);
  for (int st = 0; st < 10; ++st) {
    pmms_stage<<<B * NTILES, 256, 0, stream>>>(feat, mask, mu_cur, mu_acc);
    pmms_norm<<<96, 256, 0, stream>>>(mu_acc, mu_cur, out, out + 24576, st == 9 ? 1 : 0);
  }
  // out layout: mu_f @0 (24576) | mu_b @24576 (24576) | Prob_map @49152 (131072) | P @180224 (393216)
  pmms_query<<<B * NTILES, 256, 0, stream>>>(query, mu_cur, out + 180224, out + 49152);
}